// Round 10
// baseline (72.034 us; speedup 1.0000x reference)
//
#include <hip/hip_runtime.h>
#include <hip/hip_bf16.h>
#include <cstdint>
#include <cstddef>

// B=1, S=2048, D=1024, H=16, d=64, W=64
typedef __attribute__((ext_vector_type(8))) short short8;
typedef __attribute__((ext_vector_type(4))) float f32x4;

__device__ __forceinline__ unsigned short f2bf(float f) {
  union { float f; uint32_t u; } c; c.f = f;
  uint32_t u = c.u;
  u += 0x7fffu + ((u >> 16) & 1u);
  return (unsigned short)(u >> 16);
}

__device__ __forceinline__ void gload16(const void* g, void* l) {
  __builtin_amdgcn_global_load_lds(
      (const __attribute__((address_space(1))) uint32_t*)g,
      (__attribute__((address_space(3))) uint32_t*)l, 16, 0, 0);
}

// ---------------- unified f32 -> bf16 convert ----------------
// segments (float4 units): 3 inputs x 524288, 4 weights x 262144 = 2621440
__global__ __launch_bounds__(256) void cvt_all(
    const float* __restrict__ q, const float* __restrict__ k, const float* __restrict__ v,
    const float* __restrict__ qw, const float* __restrict__ kw,
    const float* __restrict__ vw, const float* __restrict__ ow,
    unsigned short* __restrict__ qb, unsigned short* __restrict__ kb,
    unsigned short* __restrict__ vb, unsigned short* __restrict__ wqb,
    unsigned short* __restrict__ wkb, unsigned short* __restrict__ wvb,
    unsigned short* __restrict__ wob) {
  int i = blockIdx.x * 256 + threadIdx.x;
  const float* src; unsigned short* dst; int off;
  if (i < 1572864) {
    int seg = i >> 19; off = i & 524287;
    src = seg == 0 ? q : seg == 1 ? k : v;
    dst = seg == 0 ? qb : seg == 1 ? kb : vb;
  } else {
    int t = i - 1572864;
    int seg = t >> 18; off = t & 262143;
    src = seg == 0 ? qw : seg == 1 ? kw : seg == 2 ? vw : ow;
    dst = seg == 0 ? wqb : seg == 1 ? wkb : seg == 2 ? wvb : wob;
  }
  float4 x = reinterpret_cast<const float4*>(src)[off];
  ushort4 o;
  o.x = f2bf(x.x); o.y = f2bf(x.y); o.z = f2bf(x.z); o.w = f2bf(x.w);
  reinterpret_cast<ushort4*>(dst)[off] = o;
}

// bank-swizzled LDS fragment read: tile rows of 64 shorts (BK=64), slot map
// s = sl ^ (row&7) -> b128 reads are 2-way (free) instead of 8-way.
__device__ __forceinline__ short8 ldswz64(const unsigned short* base, int row, int sl) {
  const int s = sl ^ (row & 7);
  return *reinterpret_cast<const short8*>(
      (const char*)base + row * 128 + s * 16);
}

// ---------------- fused QKV GEMM + RoPE + V-transpose ----------------
// out = A @ W^T + b (bf16 inputs via cvt_all).  BM=256, BN=128, BK=64,
// 512 threads / 8 waves, per-wave 64x64 output (best LDS bytes/FLOP),
// double-buffered gload_lds with pre-swizzled global source (rule #21).
// grid (24,8) = 192 blocks = 1/CU, balanced; bijective XCD swizzle (24/XCD).
// which 0: q -> rope(q)*0.125 bf16 [2048][1024]
// which 1: k -> rope(k)       bf16 [2048][1024]
// which 2: v -> vT            bf16 [1024][2048]  (transposed)
__global__ __launch_bounds__(512) void qkv_gemm(
    const unsigned short* __restrict__ Aq, const unsigned short* __restrict__ Ak,
    const unsigned short* __restrict__ Av,
    const unsigned short* __restrict__ Wq, const unsigned short* __restrict__ Wk,
    const unsigned short* __restrict__ Wv,
    const float* __restrict__ bq, const float* __restrict__ bk,
    const float* __restrict__ bv,
    unsigned short* __restrict__ Oq, unsigned short* __restrict__ Ok,
    unsigned short* __restrict__ OvT) {
  __shared__ __align__(16) unsigned short As[2][256][64];   // 64 KB
  __shared__ __align__(16) unsigned short Bs[2][128][64];   // 32 KB
  const int tid = threadIdx.x;
  const int w = tid >> 6, l = tid & 63;

  // bijective XCD swizzle: 192 blocks, 8 XCDs, 24 consecutive swz per XCD
  const int flat = blockIdx.y * 24 + blockIdx.x;
  const int swz = (flat & 7) * 24 + (flat >> 3);
  const int which = swz >> 6;          // 0..2  (64 tiles per which)
  const int rem = swz & 63;
  const int m0 = (rem >> 3) * 256;     // 8 m-tiles
  const int n0 = (rem & 7) * 128;      // 8 n-tiles

  const unsigned short* A = which == 0 ? Aq : which == 1 ? Ak : Av;
  const unsigned short* W = which == 0 ? Wq : which == 1 ? Wk : Wv;

  f32x4 acc[4][4];
#pragma unroll
  for (int a = 0; a < 4; ++a)
#pragma unroll
    for (int b = 0; b < 4; ++b) acc[a][b] = (f32x4){0.f, 0.f, 0.f, 0.f};

  const int wm = w >> 1, wn = w & 1;   // wave tile: rows wm*64, cols wn*64
  const int lr = l & 15, kq = l >> 4;  // kq in 0..3

  // staging: slot q -> (row = q>>3, sx = q&7); global slice s = sx ^ (row&7).
  const int srow = tid >> 3;              // 0..63
  const int ss = (tid & 7) ^ (srow & 7);  // pre-swizzled source slice
  const unsigned short* pa = A + (size_t)(m0 + srow) * 1024 + ss * 8;
  const unsigned short* pw = W + (size_t)(n0 + srow) * 1024 + ss * 8;

  auto stage = [&](int b, int kt) {
    const int k0 = kt * 64;
#pragma unroll
    for (int i = 0; i < 4; ++i)   // A rows m0 + i*64 + srow
      gload16(pa + (size_t)i * 65536 + k0, (char*)&As[b][0][0] + i * 8192 + tid * 16);
#pragma unroll
    for (int i = 0; i < 2; ++i)   // B rows n0 + i*64 + srow
      gload16(pw + (size_t)i * 65536 + k0, (char*)&Bs[b][0][0] + i * 8192 + tid * 16);
  };

  stage(0, 0);
  __syncthreads();

  for (int kt = 0; kt < 16; ++kt) {
    const int cur = kt & 1;
    if (kt < 15) stage(cur ^ 1, kt + 1);   // prefetch next, no wait
    short8 af[4][2], bf[4][2];
#pragma unroll
    for (int kk = 0; kk < 2; ++kk)
#pragma unroll
      for (int f = 0; f < 4; ++f) {
        af[f][kk] = ldswz64(&As[cur][0][0], wm * 64 + f * 16 + lr, kk * 4 + kq);
        bf[f][kk] = ldswz64(&Bs[cur][0][0], wn * 64 + f * 16 + lr, kk * 4 + kq);
      }
#pragma unroll
    for (int kk = 0; kk < 2; ++kk)
#pragma unroll
      for (int fm = 0; fm < 4; ++fm)
#pragma unroll
        for (int fn = 0; fn < 4; ++fn)
          acc[fm][fn] = __builtin_amdgcn_mfma_f32_16x16x32_bf16(
              af[fm][kk], bf[fn][kk], acc[fm][fn], 0, 0, 0);
    __syncthreads();
  }

  const float* bias = which == 0 ? bq : which == 1 ? bk : bv;
  if (which < 2) {
    // RoPE: wave's 64 cols = one head (n0+wn*64 is 64-aligned).
    // head-dim t = fn*16+lr; pair (t, t+32) = (fn, fn+2), same thread.
    unsigned short* Out = which == 0 ? Oq : Ok;
    const float sc = which == 0 ? 0.125f : 1.0f;
#pragma unroll
    for (int fn = 0; fn < 2; ++fn) {
      const int c1 = n0 + wn * 64 + fn * 16 + lr;
      const int c2 = c1 + 32;
      const int t = fn * 16 + lr;  // 0..31
      const float freq = exp2f(-(float)t * 0.415241012f);  // 10000^(-t/32)
      const float b1 = bias[c1], b2 = bias[c2];
#pragma unroll
      for (int fm = 0; fm < 4; ++fm) {
        const int rbase = m0 + wm * 64 + fm * 16 + kq * 4;
#pragma unroll
        for (int j = 0; j < 4; ++j) {
          const int s = rbase + j;
          float sn, cs;
          __sincosf((float)s * freq, &sn, &cs);
          const float x1 = acc[fm][fn][j] + b1;
          const float x2 = acc[fm][fn + 2][j] + b2;
          Out[(size_t)s * 1024 + c1] = f2bf((x1 * cs - x2 * sn) * sc);
          Out[(size_t)s * 1024 + c2] = f2bf((x1 * sn + x2 * cs) * sc);
        }
      }
    }
  } else {
    // V transposed: OvT[c][row], pack 4 consecutive rows (8B stores)
#pragma unroll
    for (int fn = 0; fn < 4; ++fn) {
      const int c = n0 + wn * 64 + fn * 16 + lr;
      const float bb = bias[c];
#pragma unroll
      for (int fm = 0; fm < 4; ++fm) {
        const int rbase = m0 + wm * 64 + fm * 16 + kq * 4;
        ushort4 o;
        o.x = f2bf(acc[fm][fn][0] + bb);
        o.y = f2bf(acc[fm][fn][1] + bb);
        o.z = f2bf(acc[fm][fn][2] + bb);
        o.w = f2bf(acc[fm][fn][3] + bb);
        *reinterpret_cast<ushort4*>(OvT + (size_t)c * 2048 + rbase) = o;
      }
    }
  }
}

// ---------------- MFMA sliding-window attention ----------------
// block = (head h, 64-query tile qb). 4 waves; wave w owns queries i0+w*16..+15.
// Key span: [i0-64, i0+64). S = Q K^T (8 16x16 tiles per wave), band mask,
// row softmax in-register, P -> swizzled LDS -> A-fragments, ctx = P V.
__global__ __launch_bounds__(256) void attn_kernel(
    const unsigned short* __restrict__ qr, const unsigned short* __restrict__ kr,
    const unsigned short* __restrict__ vT, unsigned short* __restrict__ ctx) {
  __shared__ __align__(16) unsigned short Ps[4][16][128];  // 16KB, XOR-swizzled
  const int w = threadIdx.x >> 6, l = threadIdx.x & 63;
  const int h = blockIdx.x & 15, qb = blockIdx.x >> 4;
  const int i0 = qb * 64, hb = h * 64;
  const int r = l & 15, g = l >> 4;

  // Q fragments: row = i0 + w*16 + r, k-slice = kk*32 + g*8
  short8 qf[2];
#pragma unroll
  for (int kk = 0; kk < 2; ++kk)
    qf[kk] = *reinterpret_cast<const short8*>(
        qr + (size_t)(i0 + w * 16 + r) * 1024 + hb + kk * 32 + g * 8);

  // S = Q K^T over 8 key tiles
  f32x4 acc[8];
#pragma unroll
  for (int nt = 0; nt < 8; ++nt) acc[nt] = (f32x4){0.f, 0.f, 0.f, 0.f};
#pragma unroll
  for (int nt = 0; nt < 8; ++nt) {
    int kpos = i0 - 64 + nt * 16 + r;
    int krow = kpos < 0 ? 0 : kpos;
    const unsigned short* kp = kr + (size_t)krow * 1024 + hb + g * 8;
    short8 kf0 = *reinterpret_cast<const short8*>(kp);
    short8 kf1 = *reinterpret_cast<const short8*>(kp + 32);
    acc[nt] = __builtin_amdgcn_mfma_f32_16x16x32_bf16(qf[0], kf0, acc[nt], 0, 0, 0);
    acc[nt] = __builtin_amdgcn_mfma_f32_16x16x32_bf16(qf[1], kf1, acc[nt], 0, 0, 0);
  }

  // band mask + row softmax; D layout: col=lane&15 (key), row=g*4+j (query)
#pragma unroll
  for (int j = 0; j < 4; ++j) {
    const int iq = w * 16 + g * 4 + j;        // query within 64-block
    float sv[8];
    float m = -1e30f;
#pragma unroll
    for (int nt = 0; nt < 8; ++nt) {
      const int rel = nt * 16 + r - iq;       // kpos - (i-64), valid in [0,64]
      const int kpos = i0 - 64 + nt * 16 + r;
      const bool ok = (rel >= 0) && (rel <= 64) && (kpos >= 0);
      sv[nt] = ok ? acc[nt][j] : -1e30f;
      m = fmaxf(m, sv[nt]);
    }
#pragma unroll
    for (int off = 8; off; off >>= 1) m = fmaxf(m, __shfl_xor(m, off));
    float e[8], den = 0.f;
#pragma unroll
    for (int nt = 0; nt < 8; ++nt) { e[nt] = __expf(sv[nt] - m); den += e[nt]; }
#pragma unroll
    for (int off = 8; off; off >>= 1) den += __shfl_xor(den, off);
    const float inv = 1.f / den;
    const int qrow = g * 4 + j;
    const int sw = (qrow & 7) << 3;
#pragma unroll
    for (int nt = 0; nt < 8; ++nt)
      Ps[w][qrow][(nt * 16 + r) ^ sw] = f2bf(e[nt] * inv);
  }

  __syncthreads();

  // P as A-fragments: row = r (query), k-slice = kk*32 + g*8 (key)
  short8 pf[4];
  const int swr = (r & 7) << 3;
#pragma unroll
  for (int kk = 0; kk < 4; ++kk)
    pf[kk] = *reinterpret_cast<const short8*>(&Ps[w][r][(kk * 32 + g * 8) ^ swr]);

  // ctx = P V: B-fragments from vT (row = dim, k-contiguous keys)
  f32x4 co[4];
#pragma unroll
  for (int n = 0; n < 4; ++n) co[n] = (f32x4){0.f, 0.f, 0.f, 0.f};
#pragma unroll
  for (int kk = 0; kk < 4; ++kk) {
    int cb = i0 - 64 + kk * 32 + g * 8;
    if (cb < 0) cb = 0;  // P is 0 on masked keys; clamped reads stay finite
#pragma unroll
    for (int n = 0; n < 4; ++n) {
      short8 vf = *reinterpret_cast<const short8*>(
          vT + (size_t)(hb + n * 16 + r) * 2048 + cb);
      co[n] = __builtin_amdgcn_mfma_f32_16x16x32_bf16(pf[kk], vf, co[n], 0, 0, 0);
    }
  }

  // write ctx bf16 [2048][1024]: col = hb + n*16 + r, row = i0 + w*16 + g*4 + j
#pragma unroll
  for (int n = 0; n < 4; ++n)
#pragma unroll
    for (int j = 0; j < 4; ++j)
      ctx[(size_t)(i0 + w * 16 + g * 4 + j) * 1024 + hb + n * 16 + r] = f2bf(co[n][j]);
}

// ---------------- output projection GEMM ----------------
// bf16 A (ctx) and W via gload_lds with pre-swizzled source, BK=64.
// BM=128, BN=64, double-buffered, 512 threads / 8 waves, 32x32 per wave.
// grid (16,16)=256 blocks = 1/CU; bijective XCD swizzle.
__global__ __launch_bounds__(512) void oproj_gemm(
    const unsigned short* __restrict__ A, const unsigned short* __restrict__ W,
    const float* __restrict__ bias, float* __restrict__ Out) {
  __shared__ __align__(16) unsigned short As[2][128][64];   // 32 KB
  __shared__ __align__(16) unsigned short Bs[2][64][64];    // 16 KB
  const int tid = threadIdx.x;
  const int w = tid >> 6, l = tid & 63;

  // bijective XCD swizzle: 256 blocks, 32 consecutive swz per XCD
  const int flat = blockIdx.y * 16 + blockIdx.x;
  const int swz = (flat & 7) * 32 + (flat >> 3);
  const int n0 = (swz & 15) * 64;
  const int m0 = (swz >> 4) * 128;

  f32x4 acc[2][2];
#pragma unroll
  for (int a = 0; a < 2; ++a)
#pragma unroll
    for (int b = 0; b < 2; ++b) acc[a][b] = (f32x4){0.f, 0.f, 0.f, 0.f};

  const int wm = w >> 1, wn = w & 1;
  const int lr = l & 15, kq = l >> 4;

  const int srow = tid >> 3;              // 0..63
  const int ss = (tid & 7) ^ (srow & 7);  // pre-swizzled source slice
  const unsigned short* pa = A + (size_t)(m0 + srow) * 1024 + ss * 8;
  const unsigned short* pw = W + (size_t)(n0 + srow) * 1024 + ss * 8;

  auto stage = [&](int b, int kt) {
    const int k0 = kt * 64;
#pragma unroll
    for (int i = 0; i < 2; ++i)   // A rows m0 + i*64 + srow
      gload16(pa + (size_t)i * 65536 + k0, (char*)&As[b][0][0] + i * 8192 + tid * 16);
    gload16(pw + k0, (char*)&Bs[b][0][0] + tid * 16);
  };

  stage(0, 0);
  __syncthreads();

  for (int kt = 0; kt < 16; ++kt) {
    const int cur = kt & 1;
    if (kt < 15) stage(cur ^ 1, kt + 1);
    short8 af[2][2], bf[2][2];
#pragma unroll
    for (int kk = 0; kk < 2; ++kk)
#pragma unroll
      for (int f = 0; f < 2; ++f) {
        af[f][kk] = ldswz64(&As[cur][0][0], wm * 32 + f * 16 + lr, kk * 4 + kq);
        bf[f][kk] = ldswz64(&Bs[cur][0][0], wn * 32 + f * 16 + lr, kk * 4 + kq);
      }
#pragma unroll
    for (int kk = 0; kk < 2; ++kk)
#pragma unroll
      for (int fm = 0; fm < 2; ++fm)
#pragma unroll
        for (int fn = 0; fn < 2; ++fn)
          acc[fm][fn] = __builtin_amdgcn_mfma_f32_16x16x32_bf16(
              af[fm][kk], bf[fn][kk], acc[fm][fn], 0, 0, 0);
    __syncthreads();
  }

#pragma unroll
  for (int fm = 0; fm < 2; ++fm) {
    const int rbase = m0 + wm * 32 + fm * 16 + kq * 4;
#pragma unroll
    for (int fn = 0; fn < 2; ++fn) {
      const int c = n0 + wn * 32 + fn * 16 + lr;
      const float bb = bias[c];
#pragma unroll
      for (int j = 0; j < 4; ++j)
        Out[(size_t)(rbase + j) * 1024 + c] = acc[fm][fn][j] + bb;
    }
  }
}

extern "C" void kernel_launch(void* const* d_in, const int* in_sizes, int n_in,
                              void* d_out, int out_size, void* d_ws, size_t ws_size,
                              hipStream_t stream) {
  const float* query = (const float*)d_in[0];
  const float* key   = (const float*)d_in[1];
  const float* value = (const float*)d_in[2];
  const float* q_w = (const float*)d_in[3];
  const float* q_b = (const float*)d_in[4];
  const float* k_w = (const float*)d_in[5];
  const float* k_b = (const float*)d_in[6];
  const float* v_w = (const float*)d_in[7];
  const float* v_b = (const float*)d_in[8];
  const float* o_w = (const float*)d_in[9];
  const float* o_b = (const float*)d_in[10];
  float* out = (float*)d_out;

  unsigned short* ws = (unsigned short*)d_ws;
  unsigned short* qbf = ws;                    // 2M
  unsigned short* kbf = qbf + 2097152;         // 2M
  unsigned short* vbf = kbf + 2097152;         // 2M
  unsigned short* wqb = vbf + 2097152;         // 1M
  unsigned short* wkb = wqb + 1048576;
  unsigned short* wvb = wkb + 1048576;
  unsigned short* wob = wvb + 1048576;
  unsigned short* qrope = wob + 1048576;       // 2M bf16 [2048][1024]
  unsigned short* krope = qrope + 2097152;     // 2M
  unsigned short* vTb   = krope + 2097152;     // 2M bf16 [1024][2048]
  unsigned short* ctxb  = vTb + 2097152;       // 2M
  // total ~36 MB

  cvt_all<<<10240, 256, 0, stream>>>(query, key, value, q_w, k_w, v_w, o_w,
                                     qbf, kbf, vbf, wqb, wkb, wvb, wob);
  qkv_gemm<<<dim3(24, 8), 512, 0, stream>>>(qbf, kbf, vbf, wqb, wkb, wvb,
                                            q_b, k_b, v_b, qrope, krope, vTb);
  attn_kernel<<<512, 256, 0, stream>>>(qrope, krope, vTb, ctxb);
  oproj_gemm<<<dim3(16, 16), 512, 0, stream>>>(ctxb, wob, o_b, out);
}

// Round 11
// 67.890 us; speedup vs baseline: 1.0610x; 1.0610x over previous
//
#include <hip/hip_runtime.h>
#include <hip/hip_bf16.h>
#include <cstdint>
#include <cstddef>

// B=1, S=2048, D=1024, H=16, d=64, W=64
typedef __attribute__((ext_vector_type(8))) short short8;
typedef __attribute__((ext_vector_type(4))) float f32x4;

__device__ __forceinline__ unsigned short f2bf(float f) {
  union { float f; uint32_t u; } c; c.f = f;
  uint32_t u = c.u;
  u += 0x7fffu + ((u >> 16) & 1u);
  return (unsigned short)(u >> 16);
}

__device__ __forceinline__ void gload16(const void* g, void* l) {
  __builtin_amdgcn_global_load_lds(
      (const __attribute__((address_space(1))) uint32_t*)g,
      (__attribute__((address_space(3))) uint32_t*)l, 16, 0, 0);
}

// ---------------- unified f32 -> bf16 convert ----------------
// segments (float4 units): 3 inputs x 524288, 4 weights x 262144 = 2621440
__global__ __launch_bounds__(256) void cvt_all(
    const float* __restrict__ q, const float* __restrict__ k, const float* __restrict__ v,
    const float* __restrict__ qw, const float* __restrict__ kw,
    const float* __restrict__ vw, const float* __restrict__ ow,
    unsigned short* __restrict__ qb, unsigned short* __restrict__ kb,
    unsigned short* __restrict__ vb, unsigned short* __restrict__ wqb,
    unsigned short* __restrict__ wkb, unsigned short* __restrict__ wvb,
    unsigned short* __restrict__ wob) {
  int i = blockIdx.x * 256 + threadIdx.x;
  const float* src; unsigned short* dst; int off;
  if (i < 1572864) {
    int seg = i >> 19; off = i & 524287;
    src = seg == 0 ? q : seg == 1 ? k : v;
    dst = seg == 0 ? qb : seg == 1 ? kb : vb;
  } else {
    int t = i - 1572864;
    int seg = t >> 18; off = t & 262143;
    src = seg == 0 ? qw : seg == 1 ? kw : seg == 2 ? vw : ow;
    dst = seg == 0 ? wqb : seg == 1 ? wkb : seg == 2 ? wvb : wob;
  }
  float4 x = reinterpret_cast<const float4*>(src)[off];
  ushort4 o;
  o.x = f2bf(x.x); o.y = f2bf(x.y); o.z = f2bf(x.z); o.w = f2bf(x.w);
  reinterpret_cast<ushort4*>(dst)[off] = o;
}

// bank-swizzled LDS fragment read: tile rows of 64 shorts (BK=64), slot map
// s = sl ^ (row&7) -> b128 reads are 2-way (free) instead of 8-way.
__device__ __forceinline__ short8 ldswz64(const unsigned short* base, int row, int sl) {
  const int s = sl ^ (row & 7);
  return *reinterpret_cast<const short8*>(
      (const char*)base + row * 128 + s * 16);
}
// BK=32 variant: 4 slots/row, s = sl ^ ((row>>1)&3)
__device__ __forceinline__ short8 ldswz32(const unsigned short* base, int row, int sl) {
  const int s = sl ^ ((row >> 1) & 3);
  return *reinterpret_cast<const short8*>(
      (const char*)base + row * 64 + s * 16);
}

// ---------------- fused QKV GEMM + RoPE + V-transpose ----------------
// out = A @ W^T + b (bf16 inputs via cvt_all).  BM=128, BN=128, BK=64,
// 256 threads / 4 waves, per-wave 64x64 (0.5 LDS-reads/MFMA, m97 geometry),
// double-buffered gload_lds with pre-swizzled global source (rule #21).
// LDS 64 KB -> 2 blocks/CU (cross-block wave overlap hides barrier drain).
// grid (24,16)=384 blocks; bijective XCD swizzle (48 consecutive per XCD).
// which 0: q -> rope(q)*0.125 bf16 [2048][1024]
// which 1: k -> rope(k)       bf16 [2048][1024]
// which 2: v -> vT            bf16 [1024][2048]  (transposed)
__global__ __launch_bounds__(256) void qkv_gemm(
    const unsigned short* __restrict__ Aq, const unsigned short* __restrict__ Ak,
    const unsigned short* __restrict__ Av,
    const unsigned short* __restrict__ Wq, const unsigned short* __restrict__ Wk,
    const unsigned short* __restrict__ Wv,
    const float* __restrict__ bq, const float* __restrict__ bk,
    const float* __restrict__ bv,
    unsigned short* __restrict__ Oq, unsigned short* __restrict__ Ok,
    unsigned short* __restrict__ OvT) {
  __shared__ __align__(16) unsigned short As[2][128][64];   // 32 KB
  __shared__ __align__(16) unsigned short Bs[2][128][64];   // 32 KB
  const int tid = threadIdx.x;
  const int w = tid >> 6, l = tid & 63;

  // bijective XCD swizzle: 384 blocks, 8 XCDs, 48 consecutive swz per XCD
  const int flat = blockIdx.y * 24 + blockIdx.x;
  const int swz = (flat & 7) * 48 + (flat >> 3);
  const int which = swz >> 7;          // 0..2
  const int rem = swz & 127;
  const int m0 = (rem >> 3) * 128;     // 16 m-tiles
  const int n0 = (rem & 7) * 128;      // 8 n-tiles

  const unsigned short* A = which == 0 ? Aq : which == 1 ? Ak : Av;
  const unsigned short* W = which == 0 ? Wq : which == 1 ? Wk : Wv;

  f32x4 acc[4][4];
#pragma unroll
  for (int a = 0; a < 4; ++a)
#pragma unroll
    for (int b = 0; b < 4; ++b) acc[a][b] = (f32x4){0.f, 0.f, 0.f, 0.f};

  const int wm = w >> 1, wn = w & 1;   // wave tile: rows wm*64, cols wn*64
  const int lr = l & 15, kq = l >> 4;  // kq in 0..3

  // staging: slot q -> (row = q>>3, sx = q&7); global slice s = sx ^ (row&7).
  // 256 threads x 4 slots each per tile (rows tid>>3, +32, +64, +96;
  // (row&7) invariant under +32 so one pre-swizzled base pointer works).
  const int srow = tid >> 3;              // 0..31
  const int ss = (tid & 7) ^ (srow & 7);  // pre-swizzled source slice
  const unsigned short* pa = A + (size_t)(m0 + srow) * 1024 + ss * 8;
  const unsigned short* pw = W + (size_t)(n0 + srow) * 1024 + ss * 8;

  auto stage = [&](int b, int kt) {
    const int k0 = kt * 64;
#pragma unroll
    for (int i = 0; i < 4; ++i) {  // rows srow + 32*i
      gload16(pa + (size_t)i * 32768 + k0, (char*)&As[b][0][0] + i * 4096 + tid * 16);
      gload16(pw + (size_t)i * 32768 + k0, (char*)&Bs[b][0][0] + i * 4096 + tid * 16);
    }
  };

  stage(0, 0);
  __syncthreads();

  for (int kt = 0; kt < 16; ++kt) {
    const int cur = kt & 1;
    if (kt < 15) stage(cur ^ 1, kt + 1);   // prefetch next, no wait
    short8 af[4][2], bf[4][2];
#pragma unroll
    for (int kk = 0; kk < 2; ++kk)
#pragma unroll
      for (int f = 0; f < 4; ++f) {
        af[f][kk] = ldswz64(&As[cur][0][0], wm * 64 + f * 16 + lr, kk * 4 + kq);
        bf[f][kk] = ldswz64(&Bs[cur][0][0], wn * 64 + f * 16 + lr, kk * 4 + kq);
      }
#pragma unroll
    for (int kk = 0; kk < 2; ++kk)
#pragma unroll
      for (int fm = 0; fm < 4; ++fm)
#pragma unroll
        for (int fn = 0; fn < 4; ++fn)
          acc[fm][fn] = __builtin_amdgcn_mfma_f32_16x16x32_bf16(
              af[fm][kk], bf[fn][kk], acc[fm][fn], 0, 0, 0);
    __syncthreads();
  }

  const float* bias = which == 0 ? bq : which == 1 ? bk : bv;
  if (which < 2) {
    // RoPE: wave's 64 cols = one head (n0+wn*64 is 64-aligned).
    // head-dim t = fn*16+lr; pair (t, t+32) = (fn, fn+2), same thread.
    unsigned short* Out = which == 0 ? Oq : Ok;
    const float sc = which == 0 ? 0.125f : 1.0f;
#pragma unroll
    for (int fn = 0; fn < 2; ++fn) {
      const int c1 = n0 + wn * 64 + fn * 16 + lr;
      const int c2 = c1 + 32;
      const int t = fn * 16 + lr;  // 0..31
      const float freq = exp2f(-(float)t * 0.415241012f);  // 10000^(-t/32)
      const float b1 = bias[c1], b2 = bias[c2];
#pragma unroll
      for (int fm = 0; fm < 4; ++fm) {
        const int rbase = m0 + wm * 64 + fm * 16 + kq * 4;
#pragma unroll
        for (int j = 0; j < 4; ++j) {
          const int s = rbase + j;
          float sn, cs;
          __sincosf((float)s * freq, &sn, &cs);
          const float x1 = acc[fm][fn][j] + b1;
          const float x2 = acc[fm][fn + 2][j] + b2;
          Out[(size_t)s * 1024 + c1] = f2bf((x1 * cs - x2 * sn) * sc);
          Out[(size_t)s * 1024 + c2] = f2bf((x1 * sn + x2 * cs) * sc);
        }
      }
    }
  } else {
    // V transposed: OvT[c][row], pack 4 consecutive rows (8B stores)
#pragma unroll
    for (int fn = 0; fn < 4; ++fn) {
      const int c = n0 + wn * 64 + fn * 16 + lr;
      const float bb = bias[c];
#pragma unroll
      for (int fm = 0; fm < 4; ++fm) {
        const int rbase = m0 + wm * 64 + fm * 16 + kq * 4;
        ushort4 o;
        o.x = f2bf(acc[fm][fn][0] + bb);
        o.y = f2bf(acc[fm][fn][1] + bb);
        o.z = f2bf(acc[fm][fn][2] + bb);
        o.w = f2bf(acc[fm][fn][3] + bb);
        *reinterpret_cast<ushort4*>(OvT + (size_t)c * 2048 + rbase) = o;
      }
    }
  }
}

// ---------------- MFMA sliding-window attention ----------------
// block = (head h, 64-query tile qb). 4 waves; wave w owns queries i0+w*16..+15.
// Key span: [i0-64, i0+64). S = Q K^T (8 16x16 tiles per wave), band mask,
// row softmax in-register, P -> swizzled LDS -> A-fragments, ctx = P V.
__global__ __launch_bounds__(256) void attn_kernel(
    const unsigned short* __restrict__ qr, const unsigned short* __restrict__ kr,
    const unsigned short* __restrict__ vT, unsigned short* __restrict__ ctx) {
  __shared__ __align__(16) unsigned short Ps[4][16][128];  // 16KB, XOR-swizzled
  const int w = threadIdx.x >> 6, l = threadIdx.x & 63;
  const int h = blockIdx.x & 15, qb = blockIdx.x >> 4;
  const int i0 = qb * 64, hb = h * 64;
  const int r = l & 15, g = l >> 4;

  // Q fragments: row = i0 + w*16 + r, k-slice = kk*32 + g*8
  short8 qf[2];
#pragma unroll
  for (int kk = 0; kk < 2; ++kk)
    qf[kk] = *reinterpret_cast<const short8*>(
        qr + (size_t)(i0 + w * 16 + r) * 1024 + hb + kk * 32 + g * 8);

  // S = Q K^T over 8 key tiles
  f32x4 acc[8];
#pragma unroll
  for (int nt = 0; nt < 8; ++nt) acc[nt] = (f32x4){0.f, 0.f, 0.f, 0.f};
#pragma unroll
  for (int nt = 0; nt < 8; ++nt) {
    int kpos = i0 - 64 + nt * 16 + r;
    int krow = kpos < 0 ? 0 : kpos;
    const unsigned short* kp = kr + (size_t)krow * 1024 + hb + g * 8;
    short8 kf0 = *reinterpret_cast<const short8*>(kp);
    short8 kf1 = *reinterpret_cast<const short8*>(kp + 32);
    acc[nt] = __builtin_amdgcn_mfma_f32_16x16x32_bf16(qf[0], kf0, acc[nt], 0, 0, 0);
    acc[nt] = __builtin_amdgcn_mfma_f32_16x16x32_bf16(qf[1], kf1, acc[nt], 0, 0, 0);
  }

  // band mask + row softmax; D layout: col=lane&15 (key), row=g*4+j (query)
#pragma unroll
  for (int j = 0; j < 4; ++j) {
    const int iq = w * 16 + g * 4 + j;        // query within 64-block
    float sv[8];
    float m = -1e30f;
#pragma unroll
    for (int nt = 0; nt < 8; ++nt) {
      const int rel = nt * 16 + r - iq;       // kpos - (i-64), valid in [0,64]
      const int kpos = i0 - 64 + nt * 16 + r;
      const bool ok = (rel >= 0) && (rel <= 64) && (kpos >= 0);
      sv[nt] = ok ? acc[nt][j] : -1e30f;
      m = fmaxf(m, sv[nt]);
    }
#pragma unroll
    for (int off = 8; off; off >>= 1) m = fmaxf(m, __shfl_xor(m, off));
    float e[8], den = 0.f;
#pragma unroll
    for (int nt = 0; nt < 8; ++nt) { e[nt] = __expf(sv[nt] - m); den += e[nt]; }
#pragma unroll
    for (int off = 8; off; off >>= 1) den += __shfl_xor(den, off);
    const float inv = 1.f / den;
    const int qrow = g * 4 + j;
    const int sw = (qrow & 7) << 3;
#pragma unroll
    for (int nt = 0; nt < 8; ++nt)
      Ps[w][qrow][(nt * 16 + r) ^ sw] = f2bf(e[nt] * inv);
  }

  __syncthreads();

  // P as A-fragments: row = r (query), k-slice = kk*32 + g*8 (key)
  short8 pf[4];
  const int swr = (r & 7) << 3;
#pragma unroll
  for (int kk = 0; kk < 4; ++kk)
    pf[kk] = *reinterpret_cast<const short8*>(&Ps[w][r][(kk * 32 + g * 8) ^ swr]);

  // ctx = P V: B-fragments from vT (row = dim, k-contiguous keys)
  f32x4 co[4];
#pragma unroll
  for (int n = 0; n < 4; ++n) co[n] = (f32x4){0.f, 0.f, 0.f, 0.f};
#pragma unroll
  for (int kk = 0; kk < 4; ++kk) {
    int cb = i0 - 64 + kk * 32 + g * 8;
    if (cb < 0) cb = 0;  // P is 0 on masked keys; clamped reads stay finite
#pragma unroll
    for (int n = 0; n < 4; ++n) {
      short8 vf = *reinterpret_cast<const short8*>(
          vT + (size_t)(hb + n * 16 + r) * 2048 + cb);
      co[n] = __builtin_amdgcn_mfma_f32_16x16x32_bf16(pf[kk], vf, co[n], 0, 0, 0);
    }
  }

  // write ctx bf16 [2048][1024]: col = hb + n*16 + r, row = i0 + w*16 + g*4 + j
#pragma unroll
  for (int n = 0; n < 4; ++n)
#pragma unroll
    for (int j = 0; j < 4; ++j)
      ctx[(size_t)(i0 + w * 16 + g * 4 + j) * 1024 + hb + n * 16 + r] = f2bf(co[n][j]);
}

// ---------------- output projection GEMM ----------------
// bf16 A (ctx) and W via gload_lds with pre-swizzled source (BK=32 slot map).
// BM=128, BN=64, BK=32, double-buffered, 512 threads / 8 waves.
// wave w: rows wm*32 (wm=w>>1), cols wn*32 (wn=w&1). grid (16,16)=256 blocks.
__global__ __launch_bounds__(512) void oproj_gemm(
    const unsigned short* __restrict__ A, const unsigned short* __restrict__ W,
    const float* __restrict__ bias, float* __restrict__ Out) {
  __shared__ __align__(16) unsigned short As[2][128][32];   // 16 KB
  __shared__ __align__(16) unsigned short Bs[2][64][32];    // 8 KB
  const int tid = threadIdx.x;
  const int w = tid >> 6, l = tid & 63;

  // bijective XCD swizzle: 256 blocks, 32 consecutive swz per XCD
  const int flat = blockIdx.y * 16 + blockIdx.x;
  const int swz = (flat & 7) * 32 + (flat >> 3);
  const int n0 = (swz & 15) * 64;
  const int m0 = (swz >> 4) * 128;

  f32x4 acc[2][2];
#pragma unroll
  for (int a = 0; a < 2; ++a)
#pragma unroll
    for (int b = 0; b < 2; ++b) acc[a][b] = (f32x4){0.f, 0.f, 0.f, 0.f};

  const int wm = w >> 1, wn = w & 1;
  const int lr = l & 15, kq = l >> 4;

  // staging slot q = tid: row = q>>2, sx = q&3, source slice s = sx^((row>>1)&3)
  const int srow = tid >> 2;                       // 0..127
  const int ss = (tid & 3) ^ ((srow >> 1) & 3);    // pre-swizzled slice
  const unsigned short* pa = A + (size_t)(m0 + srow) * 1024 + ss * 8;
  const unsigned short* pw = W + (size_t)(n0 + srow) * 1024 + ss * 8;  // rows<64 used

  auto stage = [&](int b, int kt) {
    const int k0 = kt * 32;
    gload16(pa + k0, (char*)&As[b][0][0] + tid * 16);
    if (tid < 256)
      gload16(pw + k0, (char*)&Bs[b][0][0] + tid * 16);
  };

  stage(0, 0);
  __syncthreads();

  for (int kt = 0; kt < 32; ++kt) {
    const int cur = kt & 1;
    if (kt < 31) stage(cur ^ 1, kt + 1);
    short8 af[2], bf[2];
#pragma unroll
    for (int f = 0; f < 2; ++f)
      af[f] = ldswz32(&As[cur][0][0], wm * 32 + f * 16 + lr, kq);
#pragma unroll
    for (int f = 0; f < 2; ++f)
      bf[f] = ldswz32(&Bs[cur][0][0], wn * 32 + f * 16 + lr, kq);
#pragma unroll
    for (int fm = 0; fm < 2; ++fm)
#pragma unroll
      for (int fn = 0; fn < 2; ++fn)
        acc[fm][fn] = __builtin_amdgcn_mfma_f32_16x16x32_bf16(af[fm], bf[fn], acc[fm][fn], 0, 0, 0);
    __syncthreads();
  }

#pragma unroll
  for (int fm = 0; fm < 2; ++fm) {
    const int rbase = m0 + wm * 32 + fm * 16 + kq * 4;
#pragma unroll
    for (int fn = 0; fn < 2; ++fn) {
      const int c = n0 + wn * 32 + fn * 16 + lr;
      const float bb = bias[c];
#pragma unroll
      for (int j = 0; j < 4; ++j)
        Out[(size_t)(rbase + j) * 1024 + c] = acc[fm][fn][j] + bb;
    }
  }
}

extern "C" void kernel_launch(void* const* d_in, const int* in_sizes, int n_in,
                              void* d_out, int out_size, void* d_ws, size_t ws_size,
                              hipStream_t stream) {
  const float* query = (const float*)d_in[0];
  const float* key   = (const float*)d_in[1];
  const float* value = (const float*)d_in[2];
  const float* q_w = (const float*)d_in[3];
  const float* q_b = (const float*)d_in[4];
  const float* k_w = (const float*)d_in[5];
  const float* k_b = (const float*)d_in[6];
  const float* v_w = (const float*)d_in[7];
  const float* v_b = (const float*)d_in[8];
  const float* o_w = (const float*)d_in[9];
  const float* o_b = (const float*)d_in[10];
  float* out = (float*)d_out;

  unsigned short* ws = (unsigned short*)d_ws;
  unsigned short* qbf = ws;                    // 2M
  unsigned short* kbf = qbf + 2097152;         // 2M
  unsigned short* vbf = kbf + 2097152;         // 2M
  unsigned short* wqb = vbf + 2097152;         // 1M
  unsigned short* wkb = wqb + 1048576;
  unsigned short* wvb = wkb + 1048576;
  unsigned short* wob = wvb + 1048576;
  unsigned short* qrope = wob + 1048576;       // 2M bf16 [2048][1024]
  unsigned short* krope = qrope + 2097152;     // 2M
  unsigned short* vTb   = krope + 2097152;     // 2M bf16 [1024][2048]
  unsigned short* ctxb  = vTb + 2097152;       // 2M
  // total ~36 MB

  cvt_all<<<10240, 256, 0, stream>>>(query, key, value, q_w, k_w, v_w, o_w,
                                     qbf, kbf, vbf, wqb, wkb, wvb, wob);
  qkv_gemm<<<dim3(24, 16), 256, 0, stream>>>(qbf, kbf, vbf, wqb, wkb, wvb,
                                             q_b, k_b, v_b, qrope, krope, vTb);
  attn_kernel<<<512, 256, 0, stream>>>(qrope, krope, vTb, ctxb);
  oproj_gemm<<<dim3(16, 16), 512, 0, stream>>>(ctxb, wob, o_b, out);
}

// Round 13
// 63.778 us; speedup vs baseline: 1.1294x; 1.0645x over previous
//
#include <hip/hip_runtime.h>
#include <hip/hip_bf16.h>
#include <cstdint>
#include <cstddef>

// B=1, S=2048, D=1024, H=16, d=64, W=64
typedef __attribute__((ext_vector_type(8))) short short8;
typedef __attribute__((ext_vector_type(4))) float f32x4;

__device__ __forceinline__ unsigned short f2bf(float f) {
  union { float f; uint32_t u; } c; c.f = f;
  uint32_t u = c.u;
  u += 0x7fffu + ((u >> 16) & 1u);
  return (unsigned short)(u >> 16);
}

__device__ __forceinline__ void gload16(const void* g, void* l) {
  __builtin_amdgcn_global_load_lds(
      (const __attribute__((address_space(1))) uint32_t*)g,
      (__attribute__((address_space(3))) uint32_t*)l, 16, 0, 0);
}

// ---------------- unified f32 -> bf16 convert ----------------
// segments (float4 units): 3 inputs x 524288, 4 weights x 262144 = 2621440
__global__ __launch_bounds__(256) void cvt_all(
    const float* __restrict__ q, const float* __restrict__ k, const float* __restrict__ v,
    const float* __restrict__ qw, const float* __restrict__ kw,
    const float* __restrict__ vw, const float* __restrict__ ow,
    unsigned short* __restrict__ qb, unsigned short* __restrict__ kb,
    unsigned short* __restrict__ vb, unsigned short* __restrict__ wqb,
    unsigned short* __restrict__ wkb, unsigned short* __restrict__ wvb,
    unsigned short* __restrict__ wob) {
  int i = blockIdx.x * 256 + threadIdx.x;
  const float* src; unsigned short* dst; int off;
  if (i < 1572864) {
    int seg = i >> 19; off = i & 524287;
    src = seg == 0 ? q : seg == 1 ? k : v;
    dst = seg == 0 ? qb : seg == 1 ? kb : vb;
  } else {
    int t = i - 1572864;
    int seg = t >> 18; off = t & 262143;
    src = seg == 0 ? qw : seg == 1 ? kw : seg == 2 ? vw : ow;
    dst = seg == 0 ? wqb : seg == 1 ? wkb : seg == 2 ? wvb : wob;
  }
  float4 x = reinterpret_cast<const float4*>(src)[off];
  ushort4 o;
  o.x = f2bf(x.x); o.y = f2bf(x.y); o.z = f2bf(x.z); o.w = f2bf(x.w);
  reinterpret_cast<ushort4*>(dst)[off] = o;
}

// bank-swizzled LDS fragment read: tile rows of 64 shorts (BK=64), slot map
// s = sl ^ (row&7) -> b128 reads are 2-way (free) instead of 8-way.
__device__ __forceinline__ short8 ldswz64(const unsigned short* base, int row, int sl) {
  const int s = sl ^ (row & 7);
  return *reinterpret_cast<const short8*>(
      (const char*)base + row * 128 + s * 16);
}
// BK=32 variant: 4 slots/row, s = sl ^ ((row>>1)&3)
__device__ __forceinline__ short8 ldswz32(const unsigned short* base, int row, int sl) {
  const int s = sl ^ ((row >> 1) & 3);
  return *reinterpret_cast<const short8*>(
      (const char*)base + row * 64 + s * 16);
}

// ---------------- fused QKV GEMM + RoPE + V-transpose ----------------
// out = A @ W^T + b (bf16 inputs via cvt_all).  BM=128, BN=128, BK=64,
// double-buffered gload_lds with pre-swizzled global source (rule #21),
// 512 threads / 8 waves; wave w: rows (w>>1)*32, cols (w&1)*64.
// XCD swizzle: each XCD gets contiguous swz range (384 % 8 == 0, bijective).
// which 0: q -> rope(q)*0.125 bf16 [2048][1024]
// which 1: k -> rope(k)       bf16 [2048][1024]
// which 2: v -> vT            bf16 [1024][2048]  (transposed)
__global__ __launch_bounds__(512) void qkv_gemm(
    const unsigned short* __restrict__ Aq, const unsigned short* __restrict__ Ak,
    const unsigned short* __restrict__ Av,
    const unsigned short* __restrict__ Wq, const unsigned short* __restrict__ Wk,
    const unsigned short* __restrict__ Wv,
    const float* __restrict__ bq, const float* __restrict__ bk,
    const float* __restrict__ bv,
    unsigned short* __restrict__ Oq, unsigned short* __restrict__ Ok,
    unsigned short* __restrict__ OvT) {
  __shared__ __align__(16) unsigned short As[2][128][64];   // 32 KB
  __shared__ __align__(16) unsigned short Bs[2][128][64];   // 32 KB
  const int tid = threadIdx.x;
  const int w = tid >> 6, l = tid & 63;

  // bijective XCD swizzle: 384 blocks, 8 XCDs, 48 consecutive swz per XCD
  const int flat = blockIdx.y * 24 + blockIdx.x;
  const int swz = (flat & 7) * 48 + (flat >> 3);
  const int which = swz >> 7;          // 0..2
  const int rem = swz & 127;
  const int m0 = (rem >> 3) * 128;     // 16 m-tiles
  const int n0 = (rem & 7) * 128;      // 8 n-tiles

  const unsigned short* A = which == 0 ? Aq : which == 1 ? Ak : Av;
  const unsigned short* W = which == 0 ? Wq : which == 1 ? Wk : Wv;

  f32x4 acc[2][4];
#pragma unroll
  for (int a = 0; a < 2; ++a)
#pragma unroll
    for (int b = 0; b < 4; ++b) acc[a][b] = (f32x4){0.f, 0.f, 0.f, 0.f};

  const int wm = w >> 1, wn = w & 1;
  const int lr = l & 15, kq = l >> 4;  // kq in 0..3

  // staging: lane tid fills slots tid and tid+512 (rows 0..63 / 64..127).
  // slot q -> (row = q>>3, sx = q&7); global slice s = sx ^ (row&7).
  const int srow = tid >> 3;            // 0..63
  const int ss = (tid & 7) ^ (srow & 7);  // pre-swizzled source slice
  const unsigned short* pa0 = A + (size_t)(m0 + srow) * 1024 + ss * 8;
  const unsigned short* pa1 = A + (size_t)(m0 + 64 + srow) * 1024 + ss * 8;
  const unsigned short* pw0 = W + (size_t)(n0 + srow) * 1024 + ss * 8;
  const unsigned short* pw1 = W + (size_t)(n0 + 64 + srow) * 1024 + ss * 8;

  auto stage = [&](int b, int kt) {
    const int k0 = kt * 64;
    gload16(pa0 + k0, (char*)&As[b][0][0] + tid * 16);
    gload16(pa1 + k0, (char*)&As[b][0][0] + 8192 + tid * 16);
    gload16(pw0 + k0, (char*)&Bs[b][0][0] + tid * 16);
    gload16(pw1 + k0, (char*)&Bs[b][0][0] + 8192 + tid * 16);
  };

  stage(0, 0);
  __syncthreads();

  for (int kt = 0; kt < 16; ++kt) {
    const int cur = kt & 1;
    if (kt < 15) stage(cur ^ 1, kt + 1);   // prefetch next, no wait
    short8 af[2][2], bf[4][2];
#pragma unroll
    for (int kk = 0; kk < 2; ++kk) {
#pragma unroll
      for (int f = 0; f < 2; ++f)
        af[f][kk] = ldswz64(&As[cur][0][0], wm * 32 + f * 16 + lr, kk * 4 + kq);
#pragma unroll
      for (int f = 0; f < 4; ++f)
        bf[f][kk] = ldswz64(&Bs[cur][0][0], wn * 64 + f * 16 + lr, kk * 4 + kq);
    }
#pragma unroll
    for (int kk = 0; kk < 2; ++kk)
#pragma unroll
      for (int fm = 0; fm < 2; ++fm)
#pragma unroll
        for (int fn = 0; fn < 4; ++fn)
          acc[fm][fn] = __builtin_amdgcn_mfma_f32_16x16x32_bf16(
              af[fm][kk], bf[fn][kk], acc[fm][fn], 0, 0, 0);
    __syncthreads();
  }

  const float* bias = which == 0 ? bq : which == 1 ? bk : bv;
  if (which < 2) {
    // RoPE: wave's 64 cols = one head (n0+wn*64 is 64-aligned).
    // head-dim t = fn*16+lr; pair (t, t+32) = (fn, fn+2), same thread.
    unsigned short* Out = which == 0 ? Oq : Ok;
    const float sc = which == 0 ? 0.125f : 1.0f;
#pragma unroll
    for (int fn = 0; fn < 2; ++fn) {
      const int c1 = n0 + wn * 64 + fn * 16 + lr;
      const int c2 = c1 + 32;
      const int t = fn * 16 + lr;  // 0..31
      const float freq = exp2f(-(float)t * 0.415241012f);  // 10000^(-t/32)
      const float b1 = bias[c1], b2 = bias[c2];
#pragma unroll
      for (int fm = 0; fm < 2; ++fm) {
        const int rbase = m0 + wm * 32 + fm * 16 + kq * 4;
#pragma unroll
        for (int j = 0; j < 4; ++j) {
          const int s = rbase + j;
          float sn, cs;
          __sincosf((float)s * freq, &sn, &cs);
          const float x1 = acc[fm][fn][j] + b1;
          const float x2 = acc[fm][fn + 2][j] + b2;
          Out[(size_t)s * 1024 + c1] = f2bf((x1 * cs - x2 * sn) * sc);
          Out[(size_t)s * 1024 + c2] = f2bf((x1 * sn + x2 * cs) * sc);
        }
      }
    }
  } else {
    // V transposed: OvT[c][row], pack 4 consecutive rows (8B stores)
#pragma unroll
    for (int fn = 0; fn < 4; ++fn) {
      const int c = n0 + wn * 64 + fn * 16 + lr;
      const float bb = bias[c];
#pragma unroll
      for (int fm = 0; fm < 2; ++fm) {
        const int rbase = m0 + wm * 32 + fm * 16 + kq * 4;
        ushort4 o;
        o.x = f2bf(acc[fm][fn][0] + bb);
        o.y = f2bf(acc[fm][fn][1] + bb);
        o.z = f2bf(acc[fm][fn][2] + bb);
        o.w = f2bf(acc[fm][fn][3] + bb);
        *reinterpret_cast<ushort4*>(OvT + (size_t)c * 2048 + rbase) = o;
      }
    }
  }
}

// ---------------- MFMA sliding-window attention ----------------
// block = (head h, 64-query tile qb). 4 waves; wave w owns queries i0+w*16..+15.
// Key span: [i0-64, i0+64). S = Q K^T (8 16x16 tiles per wave), band mask,
// row softmax in-register, P -> swizzled LDS -> A-fragments, ctx = P V.
// s_setprio(1) wraps MFMA clusters (T5, m191: helps independent-wave attn).
__global__ __launch_bounds__(256) void attn_kernel(
    const unsigned short* __restrict__ qr, const unsigned short* __restrict__ kr,
    const unsigned short* __restrict__ vT, unsigned short* __restrict__ ctx) {
  __shared__ __align__(16) unsigned short Ps[4][16][128];  // 16KB, XOR-swizzled
  const int w = threadIdx.x >> 6, l = threadIdx.x & 63;
  const int h = blockIdx.x & 15, qb = blockIdx.x >> 4;
  const int i0 = qb * 64, hb = h * 64;
  const int r = l & 15, g = l >> 4;

  // Q fragments: row = i0 + w*16 + r, k-slice = kk*32 + g*8
  short8 qf[2];
#pragma unroll
  for (int kk = 0; kk < 2; ++kk)
    qf[kk] = *reinterpret_cast<const short8*>(
        qr + (size_t)(i0 + w * 16 + r) * 1024 + hb + kk * 32 + g * 8);

  // S = Q K^T over 8 key tiles
  f32x4 acc[8];
#pragma unroll
  for (int nt = 0; nt < 8; ++nt) acc[nt] = (f32x4){0.f, 0.f, 0.f, 0.f};
#pragma unroll
  for (int nt = 0; nt < 8; ++nt) {
    int kpos = i0 - 64 + nt * 16 + r;
    int krow = kpos < 0 ? 0 : kpos;
    const unsigned short* kp = kr + (size_t)krow * 1024 + hb + g * 8;
    short8 kf0 = *reinterpret_cast<const short8*>(kp);
    short8 kf1 = *reinterpret_cast<const short8*>(kp + 32);
    __builtin_amdgcn_s_setprio(1);
    acc[nt] = __builtin_amdgcn_mfma_f32_16x16x32_bf16(qf[0], kf0, acc[nt], 0, 0, 0);
    acc[nt] = __builtin_amdgcn_mfma_f32_16x16x32_bf16(qf[1], kf1, acc[nt], 0, 0, 0);
    __builtin_amdgcn_s_setprio(0);
  }

  // band mask + row softmax; D layout: col=lane&15 (key), row=g*4+j (query)
#pragma unroll
  for (int j = 0; j < 4; ++j) {
    const int iq = w * 16 + g * 4 + j;        // query within 64-block
    float sv[8];
    float m = -1e30f;
#pragma unroll
    for (int nt = 0; nt < 8; ++nt) {
      const int rel = nt * 16 + r - iq;       // kpos - (i-64), valid in [0,64]
      const int kpos = i0 - 64 + nt * 16 + r;
      const bool ok = (rel >= 0) && (rel <= 64) && (kpos >= 0);
      sv[nt] = ok ? acc[nt][j] : -1e30f;
      m = fmaxf(m, sv[nt]);
    }
#pragma unroll
    for (int off = 8; off; off >>= 1) m = fmaxf(m, __shfl_xor(m, off));
    float e[8], den = 0.f;
#pragma unroll
    for (int nt = 0; nt < 8; ++nt) { e[nt] = __expf(sv[nt] - m); den += e[nt]; }
#pragma unroll
    for (int off = 8; off; off >>= 1) den += __shfl_xor(den, off);
    const float inv = 1.f / den;
    const int qrow = g * 4 + j;
    const int sw = (qrow & 7) << 3;
#pragma unroll
    for (int nt = 0; nt < 8; ++nt)
      Ps[w][qrow][(nt * 16 + r) ^ sw] = f2bf(e[nt] * inv);
  }

  __syncthreads();

  // P as A-fragments: row = r (query), k-slice = kk*32 + g*8 (key)
  short8 pf[4];
  const int swr = (r & 7) << 3;
#pragma unroll
  for (int kk = 0; kk < 4; ++kk)
    pf[kk] = *reinterpret_cast<const short8*>(&Ps[w][r][(kk * 32 + g * 8) ^ swr]);

  // ctx = P V: B-fragments from vT (row = dim, k-contiguous keys)
  f32x4 co[4];
#pragma unroll
  for (int n = 0; n < 4; ++n) co[n] = (f32x4){0.f, 0.f, 0.f, 0.f};
#pragma unroll
  for (int kk = 0; kk < 4; ++kk) {
    int cb = i0 - 64 + kk * 32 + g * 8;
    if (cb < 0) cb = 0;  // P is 0 on masked keys; clamped reads stay finite
#pragma unroll
    for (int n = 0; n < 4; ++n) {
      short8 vf = *reinterpret_cast<const short8*>(
          vT + (size_t)(hb + n * 16 + r) * 2048 + cb);
      __builtin_amdgcn_s_setprio(1);
      co[n] = __builtin_amdgcn_mfma_f32_16x16x32_bf16(pf[kk], vf, co[n], 0, 0, 0);
      __builtin_amdgcn_s_setprio(0);
    }
  }

  // write ctx bf16 [2048][1024]: col = hb + n*16 + r, row = i0 + w*16 + g*4 + j
#pragma unroll
  for (int n = 0; n < 4; ++n)
#pragma unroll
    for (int j = 0; j < 4; ++j)
      ctx[(size_t)(i0 + w * 16 + g * 4 + j) * 1024 + hb + n * 16 + r] = f2bf(co[n][j]);
}

// ---------------- output projection GEMM ----------------
// bf16 A (ctx) and W via gload_lds with pre-swizzled source (BK=32 slot map).
// BM=128, BN=64, BK=32, double-buffered, 512 threads / 8 waves.
// wave w: rows wm*32 (wm=w>>1), cols wn*32 (wn=w&1). grid (16,16)=256 blocks.
__global__ __launch_bounds__(512) void oproj_gemm(
    const unsigned short* __restrict__ A, const unsigned short* __restrict__ W,
    const float* __restrict__ bias, float* __restrict__ Out) {
  __shared__ __align__(16) unsigned short As[2][128][32];   // 16 KB
  __shared__ __align__(16) unsigned short Bs[2][64][32];    // 8 KB
  const int tid = threadIdx.x;
  const int w = tid >> 6, l = tid & 63;

  // bijective XCD swizzle: 256 blocks, 32 consecutive swz per XCD
  const int flat = blockIdx.y * 16 + blockIdx.x;
  const int swz = (flat & 7) * 32 + (flat >> 3);
  const int n0 = (swz & 15) * 64;
  const int m0 = (swz >> 4) * 128;

  f32x4 acc[2][2];
#pragma unroll
  for (int a = 0; a < 2; ++a)
#pragma unroll
    for (int b = 0; b < 2; ++b) acc[a][b] = (f32x4){0.f, 0.f, 0.f, 0.f};

  const int wm = w >> 1, wn = w & 1;
  const int lr = l & 15, kq = l >> 4;

  // staging slot q = tid: row = q>>2, sx = q&3, source slice s = sx^((row>>1)&3)
  const int srow = tid >> 2;                       // 0..127
  const int ss = (tid & 3) ^ ((srow >> 1) & 3);    // pre-swizzled slice
  const unsigned short* pa = A + (size_t)(m0 + srow) * 1024 + ss * 8;
  const unsigned short* pw = W + (size_t)(n0 + srow) * 1024 + ss * 8;  // rows<64 used

  auto stage = [&](int b, int kt) {
    const int k0 = kt * 32;
    gload16(pa + k0, (char*)&As[b][0][0] + tid * 16);
    if (tid < 256)
      gload16(pw + k0, (char*)&Bs[b][0][0] + tid * 16);
  };

  stage(0, 0);
  __syncthreads();

  for (int kt = 0; kt < 32; ++kt) {
    const int cur = kt & 1;
    if (kt < 31) stage(cur ^ 1, kt + 1);
    short8 af[2], bf[2];
#pragma unroll
    for (int f = 0; f < 2; ++f)
      af[f] = ldswz32(&As[cur][0][0], wm * 32 + f * 16 + lr, kq);
#pragma unroll
    for (int f = 0; f < 2; ++f)
      bf[f] = ldswz32(&Bs[cur][0][0], wn * 32 + f * 16 + lr, kq);
#pragma unroll
    for (int fm = 0; fm < 2; ++fm)
#pragma unroll
      for (int fn = 0; fn < 2; ++fn)
        acc[fm][fn] = __builtin_amdgcn_mfma_f32_16x16x32_bf16(af[fm], bf[fn], acc[fm][fn], 0, 0, 0);
    __syncthreads();
  }

#pragma unroll
  for (int fm = 0; fm < 2; ++fm) {
    const int rbase = m0 + wm * 32 + fm * 16 + kq * 4;
#pragma unroll
    for (int fn = 0; fn < 2; ++fn) {
      const int c = n0 + wn * 32 + fn * 16 + lr;
      const float bb = bias[c];
#pragma unroll
      for (int j = 0; j < 4; ++j)
        Out[(size_t)(rbase + j) * 1024 + c] = acc[fm][fn][j] + bb;
    }
  }
}

extern "C" void kernel_launch(void* const* d_in, const int* in_sizes, int n_in,
                              void* d_out, int out_size, void* d_ws, size_t ws_size,
                              hipStream_t stream) {
  const float* query = (const float*)d_in[0];
  const float* key   = (const float*)d_in[1];
  const float* value = (const float*)d_in[2];
  const float* q_w = (const float*)d_in[3];
  const float* q_b = (const float*)d_in[4];
  const float* k_w = (const float*)d_in[5];
  const float* k_b = (const float*)d_in[6];
  const float* v_w = (const float*)d_in[7];
  const float* v_b = (const float*)d_in[8];
  const float* o_w = (const float*)d_in[9];
  const float* o_b = (const float*)d_in[10];
  float* out = (float*)d_out;

  unsigned short* ws = (unsigned short*)d_ws;
  unsigned short* qbf = ws;                    // 2M
  unsigned short* kbf = qbf + 2097152;         // 2M
  unsigned short* vbf = kbf + 2097152;         // 2M
  unsigned short* wqb = vbf + 2097152;         // 1M
  unsigned short* wkb = wqb + 1048576;
  unsigned short* wvb = wkb + 1048576;
  unsigned short* wob = wvb + 1048576;
  unsigned short* qrope = wob + 1048576;       // 2M bf16 [2048][1024]
  unsigned short* krope = qrope + 2097152;     // 2M
  unsigned short* vTb   = krope + 2097152;     // 2M bf16 [1024][2048]
  unsigned short* ctxb  = vTb + 2097152;       // 2M
  // total ~36 MB

  cvt_all<<<10240, 256, 0, stream>>>(query, key, value, q_w, k_w, v_w, o_w,
                                     qbf, kbf, vbf, wqb, wkb, wvb, wob);
  qkv_gemm<<<dim3(24, 16), 512, 0, stream>>>(qbf, kbf, vbf, wqb, wkb, wvb,
                                             q_b, k_b, v_b, qrope, krope, vTb);
  attn_kernel<<<512, 256, 0, stream>>>(qrope, krope, vTb, ctxb);
  oproj_gemm<<<dim3(16, 16), 512, 0, stream>>>(ctxb, wob, o_b, out);
}

// Round 14
// 63.474 us; speedup vs baseline: 1.1349x; 1.0048x over previous
//
#include <hip/hip_runtime.h>
#include <hip/hip_bf16.h>
#include <cstdint>
#include <cstddef>

// B=1, S=2048, D=1024, H=16, d=64, W=64
typedef __attribute__((ext_vector_type(8))) short short8;
typedef __attribute__((ext_vector_type(4))) float f32x4;

__device__ __forceinline__ unsigned short f2bf(float f) {
  union { float f; uint32_t u; } c; c.f = f;
  uint32_t u = c.u;
  u += 0x7fffu + ((u >> 16) & 1u);
  return (unsigned short)(u >> 16);
}

__device__ __forceinline__ void gload16(const void* g, void* l) {
  __builtin_amdgcn_global_load_lds(
      (const __attribute__((address_space(1))) uint32_t*)g,
      (__attribute__((address_space(3))) uint32_t*)l, 16, 0, 0);
}

// ---------------- unified f32 -> bf16 convert ----------------
// segments (float4 units): 3 inputs x 524288, 4 weights x 262144 = 2621440
__global__ __launch_bounds__(256) void cvt_all(
    const float* __restrict__ q, const float* __restrict__ k, const float* __restrict__ v,
    const float* __restrict__ qw, const float* __restrict__ kw,
    const float* __restrict__ vw, const float* __restrict__ ow,
    unsigned short* __restrict__ qb, unsigned short* __restrict__ kb,
    unsigned short* __restrict__ vb, unsigned short* __restrict__ wqb,
    unsigned short* __restrict__ wkb, unsigned short* __restrict__ wvb,
    unsigned short* __restrict__ wob) {
  int i = blockIdx.x * 256 + threadIdx.x;
  const float* src; unsigned short* dst; int off;
  if (i < 1572864) {
    int seg = i >> 19; off = i & 524287;
    src = seg == 0 ? q : seg == 1 ? k : v;
    dst = seg == 0 ? qb : seg == 1 ? kb : vb;
  } else {
    int t = i - 1572864;
    int seg = t >> 18; off = t & 262143;
    src = seg == 0 ? qw : seg == 1 ? kw : seg == 2 ? vw : ow;
    dst = seg == 0 ? wqb : seg == 1 ? wkb : seg == 2 ? wvb : wob;
  }
  float4 x = reinterpret_cast<const float4*>(src)[off];
  ushort4 o;
  o.x = f2bf(x.x); o.y = f2bf(x.y); o.z = f2bf(x.z); o.w = f2bf(x.w);
  reinterpret_cast<ushort4*>(dst)[off] = o;
}

// bank-swizzled LDS fragment read: tile rows of 64 shorts (BK=64), slot map
// s = sl ^ (row&7) -> b128 reads are 2-way (free) instead of 8-way.
__device__ __forceinline__ short8 ldswz64(const unsigned short* base, int row, int sl) {
  const int s = sl ^ (row & 7);
  return *reinterpret_cast<const short8*>(
      (const char*)base + row * 128 + s * 16);
}
// BK=32 variant: 4 slots/row, s = sl ^ ((row>>1)&3)
__device__ __forceinline__ short8 ldswz32(const unsigned short* base, int row, int sl) {
  const int s = sl ^ ((row >> 1) & 3);
  return *reinterpret_cast<const short8*>(
      (const char*)base + row * 64 + s * 16);
}

// ---------------- fused QKV GEMM + RoPE + V-transpose ----------------
// out = A @ W^T + b (bf16 inputs via cvt_all).  BM=128, BN=64, BK=64,
// 256 threads / 4 waves; wave w: rows w*32, all 64 cols (per-wave 32x64 --
// byte-identical fragment code to round 9). LDS 48 KB -> 3 blocks/CU,
// grid 768 = exactly 3/CU, balanced (fixes round 9's 1.5/CU tail).
// Double-buffered gload_lds, pre-swizzled global source (rule #21).
// Bijective XCD swizzle: 768 % 8 == 0, 96 consecutive swz per XCD.
// which 0: q -> rope(q)*0.125 bf16 [2048][1024]
// which 1: k -> rope(k)       bf16 [2048][1024]
// which 2: v -> vT            bf16 [1024][2048]  (transposed)
__global__ __launch_bounds__(256) void qkv_gemm(
    const unsigned short* __restrict__ Aq, const unsigned short* __restrict__ Ak,
    const unsigned short* __restrict__ Av,
    const unsigned short* __restrict__ Wq, const unsigned short* __restrict__ Wk,
    const unsigned short* __restrict__ Wv,
    const float* __restrict__ bq, const float* __restrict__ bk,
    const float* __restrict__ bv,
    unsigned short* __restrict__ Oq, unsigned short* __restrict__ Ok,
    unsigned short* __restrict__ OvT) {
  __shared__ __align__(16) unsigned short As[2][128][64];   // 32 KB
  __shared__ __align__(16) unsigned short Bs[2][64][64];    // 16 KB
  const int tid = threadIdx.x;
  const int w = tid >> 6, l = tid & 63;

  // bijective XCD swizzle: 768 blocks, 8 XCDs, 96 consecutive swz per XCD
  const int flat = blockIdx.y * 48 + blockIdx.x;
  const int swz = (flat & 7) * 96 + (flat >> 3);
  const int which = swz >> 8;          // 0..2  (256 tiles per which)
  const int rem = swz & 255;
  const int m0 = (rem >> 4) * 128;     // 16 m-tiles
  const int n0 = (rem & 15) * 64;      // 16 n-tiles (64-aligned = one head)

  const unsigned short* A = which == 0 ? Aq : which == 1 ? Ak : Av;
  const unsigned short* W = which == 0 ? Wq : which == 1 ? Wk : Wv;

  f32x4 acc[2][4];
#pragma unroll
  for (int a = 0; a < 2; ++a)
#pragma unroll
    for (int b = 0; b < 4; ++b) acc[a][b] = (f32x4){0.f, 0.f, 0.f, 0.f};

  const int lr = l & 15, kq = l >> 4;  // kq in 0..3

  // staging: slot q -> (row = q>>3, sx = q&7); global slice s = sx ^ (row&7).
  // 256 threads; A = 4 slots each (rows tid>>3 + 32i), B = 2 slots.
  // (row&7) invariant under +32 -> one pre-swizzled base pointer works.
  const int srow = tid >> 3;              // 0..31
  const int ss = (tid & 7) ^ (srow & 7);  // pre-swizzled source slice
  const unsigned short* pa = A + (size_t)(m0 + srow) * 1024 + ss * 8;
  const unsigned short* pw = W + (size_t)(n0 + srow) * 1024 + ss * 8;

  auto stage = [&](int b, int kt) {
    const int k0 = kt * 64;
#pragma unroll
    for (int i = 0; i < 4; ++i)   // A rows srow + 32*i
      gload16(pa + (size_t)i * 32768 + k0, (char*)&As[b][0][0] + i * 4096 + tid * 16);
#pragma unroll
    for (int i = 0; i < 2; ++i)   // B rows srow + 32*i
      gload16(pw + (size_t)i * 32768 + k0, (char*)&Bs[b][0][0] + i * 4096 + tid * 16);
  };

  stage(0, 0);
  __syncthreads();

  for (int kt = 0; kt < 16; ++kt) {
    const int cur = kt & 1;
    if (kt < 15) stage(cur ^ 1, kt + 1);   // prefetch next, no wait
    short8 af[2][2], bf[4][2];
#pragma unroll
    for (int kk = 0; kk < 2; ++kk) {
#pragma unroll
      for (int f = 0; f < 2; ++f)
        af[f][kk] = ldswz64(&As[cur][0][0], w * 32 + f * 16 + lr, kk * 4 + kq);
#pragma unroll
      for (int f = 0; f < 4; ++f)
        bf[f][kk] = ldswz64(&Bs[cur][0][0], f * 16 + lr, kk * 4 + kq);
    }
#pragma unroll
    for (int kk = 0; kk < 2; ++kk)
#pragma unroll
      for (int fm = 0; fm < 2; ++fm)
#pragma unroll
        for (int fn = 0; fn < 4; ++fn)
          acc[fm][fn] = __builtin_amdgcn_mfma_f32_16x16x32_bf16(
              af[fm][kk], bf[fn][kk], acc[fm][fn], 0, 0, 0);
    __syncthreads();
  }

  const float* bias = which == 0 ? bq : which == 1 ? bk : bv;
  if (which < 2) {
    // RoPE: block's 64 cols = one head (n0 is 64-aligned).
    // head-dim t = fn*16+lr; pair (t, t+32) = (fn, fn+2), same thread.
    unsigned short* Out = which == 0 ? Oq : Ok;
    const float sc = which == 0 ? 0.125f : 1.0f;
#pragma unroll
    for (int fn = 0; fn < 2; ++fn) {
      const int c1 = n0 + fn * 16 + lr;
      const int c2 = c1 + 32;
      const int t = fn * 16 + lr;  // 0..31
      const float freq = exp2f(-(float)t * 0.415241012f);  // 10000^(-t/32)
      const float b1 = bias[c1], b2 = bias[c2];
#pragma unroll
      for (int fm = 0; fm < 2; ++fm) {
        const int rbase = m0 + w * 32 + fm * 16 + kq * 4;
#pragma unroll
        for (int j = 0; j < 4; ++j) {
          const int s = rbase + j;
          float sn, cs;
          __sincosf((float)s * freq, &sn, &cs);
          const float x1 = acc[fm][fn][j] + b1;
          const float x2 = acc[fm][fn + 2][j] + b2;
          Out[(size_t)s * 1024 + c1] = f2bf((x1 * cs - x2 * sn) * sc);
          Out[(size_t)s * 1024 + c2] = f2bf((x1 * sn + x2 * cs) * sc);
        }
      }
    }
  } else {
    // V transposed: OvT[c][row], pack 4 consecutive rows (8B stores)
#pragma unroll
    for (int fn = 0; fn < 4; ++fn) {
      const int c = n0 + fn * 16 + lr;
      const float bb = bias[c];
#pragma unroll
      for (int fm = 0; fm < 2; ++fm) {
        const int rbase = m0 + w * 32 + fm * 16 + kq * 4;
        ushort4 o;
        o.x = f2bf(acc[fm][fn][0] + bb);
        o.y = f2bf(acc[fm][fn][1] + bb);
        o.z = f2bf(acc[fm][fn][2] + bb);
        o.w = f2bf(acc[fm][fn][3] + bb);
        *reinterpret_cast<ushort4*>(OvT + (size_t)c * 2048 + rbase) = o;
      }
    }
  }
}

// ---------------- MFMA sliding-window attention ----------------
// block = (head h, 64-query tile qb). 4 waves; wave w owns queries i0+w*16..+15.
// Key span: [i0-64, i0+64). S = Q K^T (8 16x16 tiles per wave), band mask,
// row softmax in-register, P -> swizzled LDS -> A-fragments, ctx = P V.
// s_setprio(1) wraps MFMA clusters (T5, m191: helps independent-wave attn).
__global__ __launch_bounds__(256) void attn_kernel(
    const unsigned short* __restrict__ qr, const unsigned short* __restrict__ kr,
    const unsigned short* __restrict__ vT, unsigned short* __restrict__ ctx) {
  __shared__ __align__(16) unsigned short Ps[4][16][128];  // 16KB, XOR-swizzled
  const int w = threadIdx.x >> 6, l = threadIdx.x & 63;
  const int h = blockIdx.x & 15, qb = blockIdx.x >> 4;
  const int i0 = qb * 64, hb = h * 64;
  const int r = l & 15, g = l >> 4;

  // Q fragments: row = i0 + w*16 + r, k-slice = kk*32 + g*8
  short8 qf[2];
#pragma unroll
  for (int kk = 0; kk < 2; ++kk)
    qf[kk] = *reinterpret_cast<const short8*>(
        qr + (size_t)(i0 + w * 16 + r) * 1024 + hb + kk * 32 + g * 8);

  // S = Q K^T over 8 key tiles
  f32x4 acc[8];
#pragma unroll
  for (int nt = 0; nt < 8; ++nt) acc[nt] = (f32x4){0.f, 0.f, 0.f, 0.f};
#pragma unroll
  for (int nt = 0; nt < 8; ++nt) {
    int kpos = i0 - 64 + nt * 16 + r;
    int krow = kpos < 0 ? 0 : kpos;
    const unsigned short* kp = kr + (size_t)krow * 1024 + hb + g * 8;
    short8 kf0 = *reinterpret_cast<const short8*>(kp);
    short8 kf1 = *reinterpret_cast<const short8*>(kp + 32);
    __builtin_amdgcn_s_setprio(1);
    acc[nt] = __builtin_amdgcn_mfma_f32_16x16x32_bf16(qf[0], kf0, acc[nt], 0, 0, 0);
    acc[nt] = __builtin_amdgcn_mfma_f32_16x16x32_bf16(qf[1], kf1, acc[nt], 0, 0, 0);
    __builtin_amdgcn_s_setprio(0);
  }

  // band mask + row softmax; D layout: col=lane&15 (key), row=g*4+j (query)
#pragma unroll
  for (int j = 0; j < 4; ++j) {
    const int iq = w * 16 + g * 4 + j;        // query within 64-block
    float sv[8];
    float m = -1e30f;
#pragma unroll
    for (int nt = 0; nt < 8; ++nt) {
      const int rel = nt * 16 + r - iq;       // kpos - (i-64), valid in [0,64]
      const int kpos = i0 - 64 + nt * 16 + r;
      const bool ok = (rel >= 0) && (rel <= 64) && (kpos >= 0);
      sv[nt] = ok ? acc[nt][j] : -1e30f;
      m = fmaxf(m, sv[nt]);
    }
#pragma unroll
    for (int off = 8; off; off >>= 1) m = fmaxf(m, __shfl_xor(m, off));
    float e[8], den = 0.f;
#pragma unroll
    for (int nt = 0; nt < 8; ++nt) { e[nt] = __expf(sv[nt] - m); den += e[nt]; }
#pragma unroll
    for (int off = 8; off; off >>= 1) den += __shfl_xor(den, off);
    const float inv = 1.f / den;
    const int qrow = g * 4 + j;
    const int sw = (qrow & 7) << 3;
#pragma unroll
    for (int nt = 0; nt < 8; ++nt)
      Ps[w][qrow][(nt * 16 + r) ^ sw] = f2bf(e[nt] * inv);
  }

  __syncthreads();

  // P as A-fragments: row = r (query), k-slice = kk*32 + g*8 (key)
  short8 pf[4];
  const int swr = (r & 7) << 3;
#pragma unroll
  for (int kk = 0; kk < 4; ++kk)
    pf[kk] = *reinterpret_cast<const short8*>(&Ps[w][r][(kk * 32 + g * 8) ^ swr]);

  // ctx = P V: B-fragments from vT (row = dim, k-contiguous keys)
  f32x4 co[4];
#pragma unroll
  for (int n = 0; n < 4; ++n) co[n] = (f32x4){0.f, 0.f, 0.f, 0.f};
#pragma unroll
  for (int kk = 0; kk < 4; ++kk) {
    int cb = i0 - 64 + kk * 32 + g * 8;
    if (cb < 0) cb = 0;  // P is 0 on masked keys; clamped reads stay finite
#pragma unroll
    for (int n = 0; n < 4; ++n) {
      short8 vf = *reinterpret_cast<const short8*>(
          vT + (size_t)(hb + n * 16 + r) * 2048 + cb);
      __builtin_amdgcn_s_setprio(1);
      co[n] = __builtin_amdgcn_mfma_f32_16x16x32_bf16(pf[kk], vf, co[n], 0, 0, 0);
      __builtin_amdgcn_s_setprio(0);
    }
  }

  // write ctx bf16 [2048][1024]: col = hb + n*16 + r, row = i0 + w*16 + g*4 + j
#pragma unroll
  for (int n = 0; n < 4; ++n)
#pragma unroll
    for (int j = 0; j < 4; ++j)
      ctx[(size_t)(i0 + w * 16 + g * 4 + j) * 1024 + hb + n * 16 + r] = f2bf(co[n][j]);
}

// ---------------- output projection GEMM ----------------
// bf16 A (ctx) and W via gload_lds with pre-swizzled source (BK=32 slot map).
// BM=128, BN=64, BK=32, double-buffered, 512 threads / 8 waves.
// wave w: rows wm*32 (wm=w>>1), cols wn*32 (wn=w&1). grid (16,16)=256 blocks.
__global__ __launch_bounds__(512) void oproj_gemm(
    const unsigned short* __restrict__ A, const unsigned short* __restrict__ W,
    const float* __restrict__ bias, float* __restrict__ Out) {
  __shared__ __align__(16) unsigned short As[2][128][32];   // 16 KB
  __shared__ __align__(16) unsigned short Bs[2][64][32];    // 8 KB
  const int tid = threadIdx.x;
  const int w = tid >> 6, l = tid & 63;

  // bijective XCD swizzle: 256 blocks, 32 consecutive swz per XCD
  const int flat = blockIdx.y * 16 + blockIdx.x;
  const int swz = (flat & 7) * 32 + (flat >> 3);
  const int n0 = (swz & 15) * 64;
  const int m0 = (swz >> 4) * 128;

  f32x4 acc[2][2];
#pragma unroll
  for (int a = 0; a < 2; ++a)
#pragma unroll
    for (int b = 0; b < 2; ++b) acc[a][b] = (f32x4){0.f, 0.f, 0.f, 0.f};

  const int wm = w >> 1, wn = w & 1;
  const int lr = l & 15, kq = l >> 4;

  // staging slot q = tid: row = q>>2, sx = q&3, source slice s = sx^((row>>1)&3)
  const int srow = tid >> 2;                       // 0..127
  const int ss = (tid & 3) ^ ((srow >> 1) & 3);    // pre-swizzled slice
  const unsigned short* pa = A + (size_t)(m0 + srow) * 1024 + ss * 8;
  const unsigned short* pw = W + (size_t)(n0 + srow) * 1024 + ss * 8;  // rows<64 used

  auto stage = [&](int b, int kt) {
    const int k0 = kt * 32;
    gload16(pa + k0, (char*)&As[b][0][0] + tid * 16);
    if (tid < 256)
      gload16(pw + k0, (char*)&Bs[b][0][0] + tid * 16);
  };

  stage(0, 0);
  __syncthreads();

  for (int kt = 0; kt < 32; ++kt) {
    const int cur = kt & 1;
    if (kt < 31) stage(cur ^ 1, kt + 1);
    short8 af[2], bf[2];
#pragma unroll
    for (int f = 0; f < 2; ++f)
      af[f] = ldswz32(&As[cur][0][0], wm * 32 + f * 16 + lr, kq);
#pragma unroll
    for (int f = 0; f < 2; ++f)
      bf[f] = ldswz32(&Bs[cur][0][0], wn * 32 + f * 16 + lr, kq);
#pragma unroll
    for (int fm = 0; fm < 2; ++fm)
#pragma unroll
      for (int fn = 0; fn < 2; ++fn)
        acc[fm][fn] = __builtin_amdgcn_mfma_f32_16x16x32_bf16(af[fm], bf[fn], acc[fm][fn], 0, 0, 0);
    __syncthreads();
  }

#pragma unroll
  for (int fm = 0; fm < 2; ++fm) {
    const int rbase = m0 + wm * 32 + fm * 16 + kq * 4;
#pragma unroll
    for (int fn = 0; fn < 2; ++fn) {
      const int c = n0 + wn * 32 + fn * 16 + lr;
      const float bb = bias[c];
#pragma unroll
      for (int j = 0; j < 4; ++j)
        Out[(size_t)(rbase + j) * 1024 + c] = acc[fm][fn][j] + bb;
    }
  }
}

extern "C" void kernel_launch(void* const* d_in, const int* in_sizes, int n_in,
                              void* d_out, int out_size, void* d_ws, size_t ws_size,
                              hipStream_t stream) {
  const float* query = (const float*)d_in[0];
  const float* key   = (const float*)d_in[1];
  const float* value = (const float*)d_in[2];
  const float* q_w = (const float*)d_in[3];
  const float* q_b = (const float*)d_in[4];
  const float* k_w = (const float*)d_in[5];
  const float* k_b = (const float*)d_in[6];
  const float* v_w = (const float*)d_in[7];
  const float* v_b = (const float*)d_in[8];
  const float* o_w = (const float*)d_in[9];
  const float* o_b = (const float*)d_in[10];
  float* out = (float*)d_out;

  unsigned short* ws = (unsigned short*)d_ws;
  unsigned short* qbf = ws;                    // 2M
  unsigned short* kbf = qbf + 2097152;         // 2M
  unsigned short* vbf = kbf + 2097152;         // 2M
  unsigned short* wqb = vbf + 2097152;         // 1M
  unsigned short* wkb = wqb + 1048576;
  unsigned short* wvb = wkb + 1048576;
  unsigned short* wob = wvb + 1048576;
  unsigned short* qrope = wob + 1048576;       // 2M bf16 [2048][1024]
  unsigned short* krope = qrope + 2097152;     // 2M
  unsigned short* vTb   = krope + 2097152;     // 2M bf16 [1024][2048]
  unsigned short* ctxb  = vTb + 2097152;       // 2M
  // total ~36 MB

  cvt_all<<<10240, 256, 0, stream>>>(query, key, value, q_w, k_w, v_w, o_w,
                                     qbf, kbf, vbf, wqb, wkb, wvb, wob);
  qkv_gemm<<<dim3(48, 16), 256, 0, stream>>>(qbf, kbf, vbf, wqb, wkb, wvb,
                                             q_b, k_b, v_b, qrope, krope, vTb);
  attn_kernel<<<512, 256, 0, stream>>>(qrope, krope, vTb, ctxb);
  oproj_gemm<<<dim3(16, 16), 512, 0, stream>>>(ctxb, wob, o_b, out);
}